// Round 6
// baseline (338.083 us; speedup 1.0000x reference)
//
#include <hip/hip_runtime.h>
#include <math.h>

#define T_ 256
#define B_ 128
#define D_ 1024
#define K_ 21
#define NB6 22  // ceil(B_/6): 6 batches (2 triples) per scan wave

typedef short v8s __attribute__((ext_vector_type(8)));
typedef float v4f __attribute__((ext_vector_type(4)));

__device__ __forceinline__ short bf16rne(float f) {
  unsigned u = __float_as_uint(f);
  u += 0x7FFFu + ((u >> 16) & 1u);  // round-nearest-even
  return (short)(u >> 16);
}
__device__ __forceinline__ float rdl(float v, int l) {
  return __int_as_float(__builtin_amdgcn_readlane(__float_as_int(v), l));
}
__device__ __forceinline__ int imax3(int a, int b, int c) {
  const int t = a > b ? a : b;  // fuses to v_max3_i32
  return t > c ? t : c;
}

typedef const __attribute__((address_space(1))) void* gas1_t;
typedef __attribute__((address_space(3))) void* las3_t;
// wave-wide async global->LDS: lane i's dword lands at lptr + 4*i
__device__ __forceinline__ void gload_lds(const float* g, float* l) {
  __builtin_amdgcn_global_load_lds((gas1_t)g, (las3_t)l, 4, 0, 0);
}

// ---------------------------------------------------------------------------
// Kernel 1: FC as bf16 MFMA GEMM (round-3 version, proven). Block = 256 thr
// (4 waves); wave wv owns k-chunk [wv*256,+256) for rows [bid*64,+64).
// Block 0 zeroes out_loss (no separate memset dispatch).
// ---------------------------------------------------------------------------
__global__ __launch_bounds__(256) void fc_kernel(
    const float* __restrict__ A, const float* __restrict__ W,
    const float* __restrict__ bias, float* __restrict__ fc,
    float* __restrict__ out_loss) {
  __shared__ float red[3][64][22];
  if (blockIdx.x == 0 && threadIdx.x == 0) *out_loss = 0.f;
  const int lane = threadIdx.x & 63;
  const int wv = threadIdx.x >> 6;
  const int m15 = lane & 15, g4 = lane >> 4;
  const int rowbase = blockIdx.x * 64;
  const int kc = wv * 256;
  const int n1 = 16 + m15;

  v8s bf[8][2];
#pragma unroll
  for (int s = 0; s < 8; ++s) {
    const float* Wp = W + (size_t)(kc + 32 * s + 8 * g4) * K_;
#pragma unroll
    for (int j = 0; j < 8; ++j) bf[s][0][j] = bf16rne(Wp[j * K_ + m15]);
    if (n1 < K_) {
#pragma unroll
      for (int j = 0; j < 8; ++j) bf[s][1][j] = bf16rne(Wp[j * K_ + n1]);
    } else {
#pragma unroll
      for (int j = 0; j < 8; ++j) bf[s][1][j] = 0;
    }
  }

  v4f acc[4][2];
#pragma unroll
  for (int m = 0; m < 4; ++m) {
    acc[m][0] = (v4f)(0.f);
    acc[m][1] = (v4f)(0.f);
  }

#pragma unroll
  for (int s = 0; s < 8; ++s) {
    v8s av[4];
#pragma unroll
    for (int m = 0; m < 4; ++m) {
      const float* Ap =
          A + (size_t)(rowbase + 16 * m + m15) * D_ + kc + 32 * s + 8 * g4;
      const float4 x = *(const float4*)Ap;
      const float4 y = *(const float4*)(Ap + 4);
      av[m][0] = bf16rne(x.x); av[m][1] = bf16rne(x.y);
      av[m][2] = bf16rne(x.z); av[m][3] = bf16rne(x.w);
      av[m][4] = bf16rne(y.x); av[m][5] = bf16rne(y.y);
      av[m][6] = bf16rne(y.z); av[m][7] = bf16rne(y.w);
    }
#pragma unroll
    for (int m = 0; m < 4; ++m) {
      acc[m][0] = __builtin_amdgcn_mfma_f32_16x16x32_bf16(av[m], bf[s][0],
                                                          acc[m][0], 0, 0, 0);
      acc[m][1] = __builtin_amdgcn_mfma_f32_16x16x32_bf16(av[m], bf[s][1],
                                                          acc[m][1], 0, 0, 0);
    }
  }

  if (wv > 0) {
#pragma unroll
    for (int m = 0; m < 4; ++m)
#pragma unroll
      for (int ri = 0; ri < 4; ++ri) {
        const int rl = 16 * m + 4 * g4 + ri;
        red[wv - 1][rl][m15] = acc[m][0][ri];
        if (n1 < K_) red[wv - 1][rl][n1] = acc[m][1][ri];
      }
  }
  __syncthreads();
  if (wv == 0) {
    const float b0 = bias[m15];
    const float b1 = (n1 < K_) ? bias[n1] : 0.f;
#pragma unroll
    for (int m = 0; m < 4; ++m)
#pragma unroll
      for (int ri = 0; ri < 4; ++ri) {
        const int rl = 16 * m + 4 * g4 + ri;
        float* o = fc + (size_t)(rowbase + rl) * K_;
        o[m15] = acc[m][0][ri] + red[0][rl][m15] + red[1][rl][m15] +
                 red[2][rl][m15] + b0;
        if (n1 < K_)
          o[n1] = acc[m][1][ri] + red[0][rl][n1] + red[1][rl][n1] +
                  red[2][rl][n1] + b1;
      }
  }
}

// ---------------------------------------------------------------------------
// Kernel 2: sequential scans, v6: TWO independent batch-triples per wave.
// lane = g*21 + jloc serves batch b0+g (triple A) and b0+3+g (triple B).
// ec[21]/tr[21] are batch-independent -> shared; only the LDS state group
// and the VALU tree double. Triple B's 7 DS reads return UNDER triple A's
// FMA/max tree -> the DS round-trip latency (the old per-step bottleneck)
// is paid once per step for 6 batches instead of once per 3.
// fc staged per 32-step chunk via global_load_lds (2 ops/row, row stride
// 128 floats), double-buffered; one vmcnt(0) per chunk, issued a chunk
// ahead. Blocks [0,22): fwd x6; [22,44): viterbi x6; [44,172): numerator.
// ---------------------------------------------------------------------------
__global__ __launch_bounds__(64) void scan_kernel(
    const float* __restrict__ fc, const int* __restrict__ tags,
    const float* __restrict__ startT, const float* __restrict__ endT,
    const float* __restrict__ trans, float* __restrict__ out_tags,
    float* __restrict__ out_loss) {
  __shared__ v4f statev[36];                // 6 groups x 24 floats (21 + pad)
  __shared__ float fcs[2][32][128];         // fc chunk double-buffer, 32 KB
  __shared__ unsigned short bp[256 * 132];  // bp[t][g6][tag], stride 132/22
  __shared__ unsigned char h2[127 * 132];   // tag@2v <- tag@(2v+2)
  __shared__ unsigned char h4[63 * 132];    // tag@4w <- tag@(4w+4)
  __shared__ unsigned char cur[6 * 256];

  const int lane = threadIdx.x;
  const int blk = blockIdx.x;

  if (blk < 2 * NB6) {
    const bool fwd = blk < NB6;
    const int bblk = fwd ? blk : blk - NB6;
    int g = lane / 21;
    if (g > 2) g = 2;
    int jloc = lane - g * 21;
    if (jloc > 20) jloc = 20;
    const int gjA = g * 21 + jloc;   // triple A column; lane63 dups lane62
    const int gjB = gjA + 63;        // triple B column
    const int b0 = bblk * 6;

    // lengths for 6 batches (uniform, via ballots); mask[t] == (t < len)
    int len[6];
#pragma unroll
    for (int k = 0; k < 6; ++k) len[k] = 0;
#pragma unroll
    for (int q = 0; q < 4; ++q) {
      const int t = q * 64 + lane;
#pragma unroll
      for (int k = 0; k < 6; ++k) {
        int bb = b0 + k;
        if (bb >= B_) bb = B_ - 1;
        len[k] += __popcll(__ballot(tags[t * B_ + bb] != 0));
      }
    }
    const int len0 = len[0], len1 = len[1], len2 = len[2];
    const int len3 = len[3], len4 = len[4], len5 = len[5];
    const int mylenA = (g == 0) ? len0 : (g == 1) ? len1 : len2;
    const int mylenB = (g == 0) ? len3 : (g == 1) ? len4 : len5;

    float* sbA = (float*)statev + g * 24;        // triple A state
    float* sbB = (float*)statev + (3 + g) * 24;  // triple B state
    const v4f* svA = (const v4f*)sbA;
    const v4f* svB = (const v4f*)sbB;

    // ---- fc staging: rows t = 32c..32c+31 -> fcs[c&1][t&31][0..125]
    // (6 contiguous batches x 21 floats; 2 wave-wide dword loads per row;
    //  cols 126..127 are pad garbage, never read)
#define STAGE(c)                                                             \
    {                                                                        \
      const float* src_ = fc + ((size_t)((c) * 32) * B_ + b0) * K_ + lane;   \
      float* dst_ = &fcs[(c) & 1][0][0];                                     \
      _Pragma("unroll")                                                      \
      for (int q_ = 0; q_ < 32; ++q_) {                                      \
        gload_lds(src_ + (size_t)q_ * (B_ * K_), dst_ + q_ * 128);           \
        gload_lds(src_ + (size_t)q_ * (B_ * K_) + 64, dst_ + q_ * 128 + 64); \
      }                                                                      \
    }
#define WAIT_VM0()                                                           \
    {                                                                        \
      asm volatile("s_waitcnt vmcnt(0)" ::: "memory");                       \
      __builtin_amdgcn_sched_barrier(0);                                     \
    }

    STAGE(0)
    WAIT_VM0()
    const float em0A = fcs[0][0][gjA];
    const float em0B = fcs[0][0][gjB];
    STAGE(1)

    const float st0 = startT[jloc];

    if (fwd) {
      // ---------------- forward / denominator (linear domain) ------------
      float ec[21];  // exp(trans[:, jloc]) — shared by both triples
#pragma unroll
      for (int i = 0; i < K_; ++i) ec[i] = __expf(trans[i * K_ + jloc]);
      float pA = __expf(st0 + em0A), pB = __expf(st0 + em0B);
      float LA = 0.f, LB = 0.f;
      sbA[jloc] = pA;
      sbB[jloc] = pB;

      for (int c = 0; c < 8; ++c) {
        const float* fb = &fcs[c & 1][0][0];
        const int t1 = c * 32 + 32;
        for (int t = c ? c * 32 : 1; t < t1; ++t) {
          const float emtA = fb[(t & 31) * 128 + gjA];
          const float emtB = fb[(t & 31) * 128 + gjB];
          const v4f A0 = svA[0], A1 = svA[1], A2 = svA[2], A3 = svA[3],
                    A4 = svA[4];
          const float A5 = sbA[20];
          const v4f B0 = svB[0], B1 = svB[1], B2 = svB[2], B3 = svB[3],
                    B4 = svB[4];
          const float B5 = sbB[20];

          // triple A tree
          float a0 = A0[0] * ec[0], a1 = A0[1] * ec[1], a2 = A0[2] * ec[2];
          a0 = fmaf(A0[3], ec[3], a0); a1 = fmaf(A1[0], ec[4], a1);
          a2 = fmaf(A1[1], ec[5], a2);
          a0 = fmaf(A1[2], ec[6], a0); a1 = fmaf(A1[3], ec[7], a1);
          a2 = fmaf(A2[0], ec[8], a2);
          a0 = fmaf(A2[1], ec[9], a0); a1 = fmaf(A2[2], ec[10], a1);
          a2 = fmaf(A2[3], ec[11], a2);
          a0 = fmaf(A3[0], ec[12], a0); a1 = fmaf(A3[1], ec[13], a1);
          a2 = fmaf(A3[2], ec[14], a2);
          a0 = fmaf(A3[3], ec[15], a0); a1 = fmaf(A4[0], ec[16], a1);
          a2 = fmaf(A4[1], ec[17], a2);
          a0 = fmaf(A4[2], ec[18], a0); a1 = fmaf(A4[3], ec[19], a1);
          a2 = fmaf(A5, ec[20], a2);
          const float pnA = ((a0 + a1) + a2) * __expf(emtA);

          // triple B tree (independent; overlaps A's latency)
          float b0_ = B0[0] * ec[0], b1_ = B0[1] * ec[1], b2_ = B0[2] * ec[2];
          b0_ = fmaf(B0[3], ec[3], b0_); b1_ = fmaf(B1[0], ec[4], b1_);
          b2_ = fmaf(B1[1], ec[5], b2_);
          b0_ = fmaf(B1[2], ec[6], b0_); b1_ = fmaf(B1[3], ec[7], b1_);
          b2_ = fmaf(B2[0], ec[8], b2_);
          b0_ = fmaf(B2[1], ec[9], b0_); b1_ = fmaf(B2[2], ec[10], b1_);
          b2_ = fmaf(B2[3], ec[11], b2_);
          b0_ = fmaf(B3[0], ec[12], b0_); b1_ = fmaf(B3[1], ec[13], b1_);
          b2_ = fmaf(B3[2], ec[14], b2_);
          b0_ = fmaf(B3[3], ec[15], b0_); b1_ = fmaf(B4[0], ec[16], b1_);
          b2_ = fmaf(B4[1], ec[17], b2_);
          b0_ = fmaf(B4[2], ec[18], b0_); b1_ = fmaf(B4[3], ec[19], b1_);
          b2_ = fmaf(B5, ec[20], b2_);
          const float pnB = ((b0_ + b1_) + b2_) * __expf(emtB);

          pA = (t < mylenA) ? pnA : pA;
          pB = (t < mylenB) ? pnB : pB;
          if ((t & 7) == 0) {  // group-uniform renorm by OLD p[0]
            const float fA = A0[0], fB = B0[0];
            pA *= __builtin_amdgcn_rcpf(fA);
            LA += __logf(fA);
            pB *= __builtin_amdgcn_rcpf(fB);
            LB += __logf(fB);
          }
          sbA[jloc] = pA;
          sbB[jloc] = pB;
        }
        if (c < 7) {
          WAIT_VM0()
          if (c + 2 < 8) STAGE(c + 2)
        }
      }

      const float eT = __expf(endT[jloc]);
      const float wA = pA * eT, wB = pB * eT;
      float res = 0.f;
#pragma unroll
      for (int gg = 0; gg < 6; ++gg) {
        if (b0 + gg < B_) {
          const int base = (gg % 3) * 21;
          float tot = 0.f;
          if (gg < 3) {
#pragma unroll
            for (int i = 0; i < K_; ++i) tot += rdl(wA, base + i);
            res += rdl(LA, base) + __logf(tot);
          } else {
#pragma unroll
            for (int i = 0; i < K_; ++i) tot += rdl(wB, base + i);
            res += rdl(LB, base) + __logf(tot);
          }
        }
      }
      if (lane == 0) atomicAdd(out_loss, res);  // +den
    } else {
      // ---------------- Viterbi ----------------
      float tr[21];  // trans[:, jloc] + 2048 — shared by both triples
#pragma unroll
      for (int i = 0; i < K_; ++i) tr[i] = trans[i * K_ + jloc] + 2048.0f;
      float scA = st0 + em0A, scB = st0 + em0B;
      sbA[jloc] = scA;
      sbB[jloc] = scB;

      for (int c = 0; c < 8; ++c) {
        const float* fb = &fcs[c & 1][0][0];
        const int t1 = c * 32 + 32;
        for (int t = c ? c * 32 : 1; t < t1; ++t) {
          const float emtA = fb[(t & 31) * 128 + gjA];
          const float emtB = fb[(t & 31) * 128 + gjB];
          const v4f A0 = svA[0], A1 = svA[1], A2 = svA[2], A3 = svA[3],
                    A4 = svA[4];
          const float A5 = sbA[20];
          const v4f B0 = svB[0], B1 = svB[1], B2 = svB[2], B3 = svB[3],
                    B4 = svB[4];
          const float B5 = sbB[20];

          // key = (bits & ~31) | (20-i): larger key <=> smaller prev tag
          // (first-argmax). All keys positive (score+2048 > 0).
#define KEY(i, V) ((__float_as_int((V) + tr[i]) & 0xFFFFFFE0) | (20 - (i)))
          const int qa0 = imax3(KEY(0, A0[0]), KEY(1, A0[1]), KEY(2, A0[2]));
          const int qa1 = imax3(KEY(3, A0[3]), KEY(4, A1[0]), KEY(5, A1[1]));
          const int qa2 = imax3(KEY(6, A1[2]), KEY(7, A1[3]), KEY(8, A2[0]));
          const int qa3 = imax3(KEY(9, A2[1]), KEY(10, A2[2]), KEY(11, A2[3]));
          const int qa4 = imax3(KEY(12, A3[0]), KEY(13, A3[1]), KEY(14, A3[2]));
          const int qa5 = imax3(KEY(15, A3[3]), KEY(16, A4[0]), KEY(17, A4[1]));
          const int qa6 = imax3(KEY(18, A4[2]), KEY(19, A4[3]), KEY(20, A5));
          const int kmA = imax3(imax3(qa0, qa1, qa2), imax3(qa3, qa4, qa5),
                                qa6);
          const int qb0 = imax3(KEY(0, B0[0]), KEY(1, B0[1]), KEY(2, B0[2]));
          const int qb1 = imax3(KEY(3, B0[3]), KEY(4, B1[0]), KEY(5, B1[1]));
          const int qb2 = imax3(KEY(6, B1[2]), KEY(7, B1[3]), KEY(8, B2[0]));
          const int qb3 = imax3(KEY(9, B2[1]), KEY(10, B2[2]), KEY(11, B2[3]));
          const int qb4 = imax3(KEY(12, B3[0]), KEY(13, B3[1]), KEY(14, B3[2]));
          const int qb5 = imax3(KEY(15, B3[3]), KEY(16, B4[0]), KEY(17, B4[1]));
          const int qb6 = imax3(KEY(18, B4[2]), KEY(19, B4[3]), KEY(20, B5));
          const int kmB = imax3(imax3(qb0, qb1, qb2), imax3(qb3, qb4, qb5),
                                qb6);
#undef KEY
          const float nxtA =
              __int_as_float(kmA & 0xFFFFFFE0) - 2048.0f + emtA;
          const float nxtB =
              __int_as_float(kmB & 0xFFFFFFE0) - 2048.0f + emtB;
          const bool mA = t < mylenA, mB = t < mylenB;
          scA = mA ? nxtA : scA;
          scB = mB ? nxtB : scB;
          sbA[jloc] = scA;
          sbB[jloc] = scB;
          const int pwA = mA ? (20 - (kmA & 31)) : jloc;
          const int pwB = mB ? (20 - (kmB & 31)) : jloc;
          bp[t * 132 + g * 22 + jloc] = (unsigned short)pwA;
          bp[t * 132 + (3 + g) * 22 + jloc] = (unsigned short)pwB;
        }
        if (c < 7) {
          WAIT_VM0()
          if (c + 2 < 8) STAGE(c + 2)
        }
      }
      __syncthreads();

      // final argmax per group (tie-break: smallest tag)
      const float eTl = endT[jloc] + 2048.0f;
      const int mykA = (__float_as_int(scA + eTl) & 0xFFFFFFE0) | (20 - jloc);
      const int mykB = (__float_as_int(scB + eTl) & 0xFFFFFFE0) | (20 - jloc);
      int last[6];
#pragma unroll
      for (int gg = 0; gg < 6; ++gg) {
        const int base = (gg % 3) * 21;
        int km = 0;
#pragma unroll
        for (int i = 0; i < K_; ++i) {
          const int ki = __builtin_amdgcn_readlane(gg < 3 ? mykA : mykB,
                                                   base + i);
          km = km > ki ? km : ki;
        }
        last[gg] = 20 - (km & 31);
      }
      const int last0 = last[0], last1 = last[1], last2 = last[2];
      const int last3 = last[3], last4 = last[4], last5 = last[5];

      // skip tables (parallel over lanes; 6 groups x 21 tags = 126/row)
      for (int i = lane; i < 127 * 126; i += 64) {
        const int v = i / 126;
        const int rem = i - v * 126;
        const int gg = rem / 21, j = rem - (rem / 21) * 21;
        h2[v * 132 + gg * 22 + j] = (unsigned char)
            bp[(2 * v + 1) * 132 + gg * 22 +
               bp[(2 * v + 2) * 132 + gg * 22 + j]];
      }
      __syncthreads();
      for (int i = lane; i < 63 * 126; i += 64) {
        const int w2 = i / 126;
        const int rem = i - w2 * 126;
        const int gg = rem / 21, j = rem - (rem / 21) * 21;
        h4[w2 * 132 + gg * 22 + j] =
            h2[(2 * w2) * 132 + gg * 22 +
               h2[(2 * w2 + 1) * 132 + gg * 22 + j]];
      }
      __syncthreads();

      // 6 parallel serial chases (lane == group)
      if (lane < 6 && b0 + lane < B_) {
        int c = (lane == 0) ? last0 : (lane == 1) ? last1
                : (lane == 2) ? last2 : (lane == 3) ? last3
                : (lane == 4) ? last4 : last5;
        cur[lane * 256 + 255] = (unsigned char)c;
        c = bp[255 * 132 + lane * 22 + c];
        cur[lane * 256 + 254] = (unsigned char)c;
        c = h2[126 * 132 + lane * 22 + c];
        cur[lane * 256 + 252] = (unsigned char)c;
        for (int w2 = 62; w2 >= 0; --w2) {
          c = h4[w2 * 132 + lane * 22 + c];
          cur[lane * 256 + 4 * w2] = (unsigned char)c;
        }
      }
      __syncthreads();
      for (int i = lane; i < 63 * 6; i += 64) {  // t = 2 mod 4
        const int gg = i / 63, ii = i - (i / 63) * 63;
        const int t = 2 + 4 * ii;
        cur[gg * 256 + t] =
            h2[(t >> 1) * 132 + gg * 22 + cur[gg * 256 + t + 2]];
      }
      __syncthreads();
      for (int i = lane; i < 127 * 6; i += 64) {  // odd t
        const int gg = i / 127, ii = i - (i / 127) * 127;
        const int t = 1 + 2 * ii;
        cur[gg * 256 + t] = (unsigned char)
            bp[(t + 1) * 132 + gg * 22 + cur[gg * 256 + t + 1]];
      }
      __syncthreads();
      for (int i = lane; i < 6 * 256; i += 64) {
        const int gg = i >> 8, t = i & 255;
        const int bb = b0 + gg;
        const int lg = (gg == 0) ? len0 : (gg == 1) ? len1
                      : (gg == 2) ? len2 : (gg == 3) ? len3
                      : (gg == 4) ? len4 : len5;
        if (bb < B_)
          out_tags[t * B_ + bb] = (t < lg) ? (float)cur[gg * 256 + t] : 0.f;
      }
    }
#undef STAGE
#undef WAIT_VM0
  } else {
    // ---------------- numerator ----------------
    const int b = blk - 2 * NB6;
    float contrib = 0.f;
#pragma unroll
    for (int q = 0; q < 4; ++q) {
      const int t = lane * 4 + q;
      const int tg = tags[t * B_ + b];
      const size_t ro = ((size_t)t * B_ + b) * K_;
      if (t == 0) {
        contrib += startT[tg] + fc[ro + tg];
      } else if (tg != 0) {
        const int pg = tags[(t - 1) * B_ + b];
        contrib += trans[pg * K_ + tg] + fc[ro + tg];
      }
      const bool isLast =
          (tg != 0) && (t == T_ - 1 || tags[(t + 1) * B_ + b] == 0);
      if (isLast) contrib += endT[tg];
    }
#pragma unroll
    for (int off = 32; off > 0; off >>= 1)
      contrib += __shfl_down(contrib, off, 64);
    if (lane == 0) atomicAdd(out_loss, -contrib);  // -num
  }
}

extern "C" void kernel_launch(void* const* d_in, const int* in_sizes, int n_in,
                              void* d_out, int out_size, void* d_ws,
                              size_t ws_size, hipStream_t stream) {
  const float* A = (const float*)d_in[0];
  const int* tags = (const int*)d_in[1];
  const float* W = (const float*)d_in[2];
  const float* bias = (const float*)d_in[3];
  const float* startT = (const float*)d_in[4];
  const float* endT = (const float*)d_in[5];
  const float* trans = (const float*)d_in[6];

  float* out_tags = (float*)d_out;
  float* out_loss = (float*)d_out + (size_t)T_ * B_;
  float* fc = (float*)d_ws;  // [t*B+b][21] f32, 2.75 MB

  fc_kernel<<<512, 256, 0, stream>>>(A, W, bias, fc, out_loss);
  scan_kernel<<<2 * NB6 + B_, 64, 0, stream>>>(fc, tags, startT, endT, trans,
                                               out_tags, out_loss);
}